// Round 1
// baseline (201.214 us; speedup 1.0000x reference)
//
#include <hip/hip_runtime.h>
#include <stdint.h>

#define BLK 256
#define IPT 4          // owner points per thread
#define SLICE 1024     // scanned-dimension slice length per block

// Monotone float -> uint transform (preserves <, total order).
__device__ __forceinline__ unsigned int ford(float f) {
    int b = __float_as_int(f);
    return (b >= 0) ? ((unsigned)b ^ 0x80000000u) : ~(unsigned)b;
}

// For each "owner" point o from A, compute argmin over scanned points s from B of
//   (|B_s|^2 - 2 * A_o . B_s)     [ == d2 minus the owner-constant |A_o|^2 ]
// Accumulates packed (ordered_value << 32 | index) via u64 atomicMin, so the
// global min has numpy-style smallest-index tie-break.
__global__ __launch_bounds__(BLK) void nn_argmin(
    const float* __restrict__ A, const float* __restrict__ B,
    unsigned long long* __restrict__ outmin)
{
    __shared__ float4 sb[BLK];
    const int o0 = blockIdx.x * (BLK * IPT) + threadIdx.x;

    float ax[IPT], ay[IPT], az[IPT];
#pragma unroll
    for (int r = 0; r < IPT; ++r) {
        int o = o0 + r * BLK;
        ax[r] = -2.0f * A[3 * o];
        ay[r] = -2.0f * A[3 * o + 1];
        az[r] = -2.0f * A[3 * o + 2];
    }

    float best[IPT];
    int   bidx[IPT];
#pragma unroll
    for (int r = 0; r < IPT; ++r) { best[r] = __int_as_float(0x7f7fffff); bidx[r] = 0; }

    const int s0 = blockIdx.y * SLICE;
    for (int st = 0; st < SLICE; st += BLK) {
        int s = s0 + st + threadIdx.x;
        float bx = B[3 * s], by = B[3 * s + 1], bz = B[3 * s + 2];
        sb[threadIdx.x] = make_float4(bx, by, bz, bx * bx + by * by + bz * bz);
        __syncthreads();
#pragma unroll 4
        for (int k = 0; k < BLK; ++k) {
            float4 q = sb[k];          // wave-uniform broadcast read
            int sj = s0 + st + k;      // scanned index increases monotonically
#pragma unroll
            for (int r = 0; r < IPT; ++r) {
                float v = fmaf(ax[r], q.x, fmaf(ay[r], q.y, fmaf(az[r], q.z, q.w)));
                if (v < best[r]) { best[r] = v; bidx[r] = sj; }  // strict <: first occurrence wins
            }
        }
        __syncthreads();
    }

#pragma unroll
    for (int r = 0; r < IPT; ++r) {
        unsigned long long packed =
            ((unsigned long long)ford(best[r]) << 32) | (unsigned)bidx[r];
        atomicMin(&outmin[o0 + r * BLK], packed);
    }
}

// Gather normals at argmin indices, accumulate mean(1 - dot) for both directions.
__global__ __launch_bounds__(BLK) void finalize_kernel(
    const unsigned long long* __restrict__ rowmin,
    const unsigned long long* __restrict__ colmin,
    const float* __restrict__ pn, const float* __restrict__ gn,
    float* __restrict__ out, int N, int M, float invN, float invM)
{
    int t = blockIdx.x * BLK + threadIdx.x;
    float c = 0.0f;
    if (t < N) {
        int j = (int)(rowmin[t] & 0xffffffffull);
        float d = pn[3 * t] * gn[3 * j] + pn[3 * t + 1] * gn[3 * j + 1]
                + pn[3 * t + 2] * gn[3 * j + 2];
        c = (1.0f - d) * invN;
    } else if (t < N + M) {
        int j = t - N;
        int i = (int)(colmin[j] & 0xffffffffull);
        float d = gn[3 * j] * pn[3 * i] + gn[3 * j + 1] * pn[3 * i + 1]
                + gn[3 * j + 2] * pn[3 * i + 2];
        c = (1.0f - d) * invM;
    }
#pragma unroll
    for (int off = 32; off > 0; off >>= 1) c += __shfl_down(c, off, 64);
    __shared__ float partial[BLK / 64];
    if ((threadIdx.x & 63) == 0) partial[threadIdx.x >> 6] = c;
    __syncthreads();
    if (threadIdx.x == 0) {
        float s = 0.0f;
#pragma unroll
        for (int w = 0; w < BLK / 64; ++w) s += partial[w];
        atomicAdd(out, s);
    }
}

extern "C" void kernel_launch(void* const* d_in, const int* in_sizes, int n_in,
                              void* d_out, int out_size, void* d_ws, size_t ws_size,
                              hipStream_t stream) {
    const float* p  = (const float*)d_in[0];   // [N,3] predicted points
    const float* pn = (const float*)d_in[1];   // [N,3] predicted normals (unit)
    const float* g  = (const float*)d_in[2];   // [M,3] gt points
    const float* gn = (const float*)d_in[3];   // [M,3] gt normals (unit)
    const int N = in_sizes[0] / 3;             // 8192
    const int M = in_sizes[2] / 3;             // 32768

    unsigned long long* rowmin = (unsigned long long*)d_ws;       // [N]
    unsigned long long* colmin = rowmin + N;                      // [M]
    float* out = (float*)d_out;

    // Init packed-min arrays to u64-max, output accumulator to 0.
    hipMemsetAsync(d_ws, 0xFF, (size_t)(N + M) * sizeof(unsigned long long), stream);
    hipMemsetAsync(d_out, 0, sizeof(float), stream);

    // Row direction: owners = predicted points (N), scan gt points (M).
    dim3 gRow(N / (BLK * IPT), M / SLICE);     // (8, 32)
    nn_argmin<<<gRow, BLK, 0, stream>>>(p, g, rowmin);

    // Col direction: owners = gt points (M), scan predicted points (N).
    dim3 gCol(M / (BLK * IPT), N / SLICE);     // (32, 8)
    nn_argmin<<<gCol, BLK, 0, stream>>>(g, p, colmin);

    int tot = N + M;
    finalize_kernel<<<(tot + BLK - 1) / BLK, BLK, 0, stream>>>(
        rowmin, colmin, pn, gn, out, N, M, 1.0f / N, 1.0f / M);
}

// Round 2
// 135.186 us; speedup vs baseline: 1.4884x; 1.4884x over previous
//
#include <hip/hip_runtime.h>
#include <stdint.h>

#define BLK 256
#define IPT 8                 // owner points per thread (8 independent min-chains)
#define OWNERS (BLK * IPT)    // 2048 owners per block
#define SLICE 512             // scanned-dimension slice per block (8 KB LDS)

typedef unsigned long long ull;

// Monotone float -> uint transform (preserves <, total order).
__device__ __forceinline__ unsigned int ford(float f) {
    int b = __float_as_int(f);
    return (b >= 0) ? ((unsigned)b ^ 0x80000000u) : ~(unsigned)b;
}

// Both NN directions in ONE launch. Blocks [0, rowBlocks) do owners=pred/scan=gt;
// the rest do owners=gt/scan=pred. For each owner o from A, argmin over scanned
// s of (|B_s|^2 - 2 A_o . B_s)  (drop the owner-constant |A_o|^2). Result merged
// via u64 atomicMin of (ordered_value<<32 | index) => numpy smallest-index ties.
__global__ __launch_bounds__(BLK) void nn_argmin_dual(
    const float* __restrict__ p, const float* __restrict__ g,
    ull* __restrict__ rowmin, ull* __restrict__ colmin,
    int rowBlocks, int rowSlices, int colSlices)
{
    __shared__ float4 sb[SLICE];

    const float* A; const float* B; ull* outmin; int id, nSlices;
    if ((int)blockIdx.x < rowBlocks) {
        id = blockIdx.x;             A = p; B = g; outmin = rowmin; nSlices = rowSlices;
    } else {
        id = blockIdx.x - rowBlocks; A = g; B = p; outmin = colmin; nSlices = colSlices;
    }
    const int chunk = id / nSlices;
    const int slice = id - chunk * nSlices;
    const int s0 = slice * SLICE;

    // Stage the whole scanned slice (coords + |B|^2) into LDS. One barrier/block.
    for (int t = threadIdx.x; t < SLICE; t += BLK) {
        int s = s0 + t;
        float bx = B[3 * s], by = B[3 * s + 1], bz = B[3 * s + 2];
        sb[t] = make_float4(bx, by, bz, bx * bx + by * by + bz * bz);
    }

    const int o0 = chunk * OWNERS + threadIdx.x;
    float ax[IPT], ay[IPT], az[IPT], best[IPT];
    int bidx[IPT];
#pragma unroll
    for (int r = 0; r < IPT; ++r) {
        int o = o0 + r * BLK;
        ax[r] = -2.0f * A[3 * o];
        ay[r] = -2.0f * A[3 * o + 1];
        az[r] = -2.0f * A[3 * o + 2];
        best[r] = __int_as_float(0x7f7fffff);
        bidx[r] = 0;
    }
    __syncthreads();

#pragma unroll 4
    for (int k = 0; k < SLICE; ++k) {
        float4 q = sb[k];        // wave-uniform broadcast read, no bank conflict
        int sj = s0 + k;         // scanned index increases monotonically
#pragma unroll
        for (int r = 0; r < IPT; ++r) {
            float v = fmaf(ax[r], q.x, fmaf(ay[r], q.y, fmaf(az[r], q.z, q.w)));
            if (v < best[r]) { best[r] = v; bidx[r] = sj; }  // strict <: first wins
        }
    }

#pragma unroll
    for (int r = 0; r < IPT; ++r) {
        ull packed = ((ull)ford(best[r]) << 32) | (unsigned)bidx[r];
        atomicMin(&outmin[o0 + r * BLK], packed);
    }
}

// Gather normals at argmin indices, accumulate mean(1 - dot) for both directions.
__global__ __launch_bounds__(BLK) void finalize_kernel(
    const ull* __restrict__ rowmin, const ull* __restrict__ colmin,
    const float* __restrict__ pn, const float* __restrict__ gn,
    float* __restrict__ out, int N, int M, float invN, float invM)
{
    int t = blockIdx.x * BLK + threadIdx.x;
    float c = 0.0f;
    if (t < N) {
        int j = (int)(rowmin[t] & 0xffffffffull);
        float d = pn[3 * t] * gn[3 * j] + pn[3 * t + 1] * gn[3 * j + 1]
                + pn[3 * t + 2] * gn[3 * j + 2];
        c = (1.0f - d) * invN;
    } else if (t < N + M) {
        int j = t - N;
        int i = (int)(colmin[j] & 0xffffffffull);
        float d = gn[3 * j] * pn[3 * i] + gn[3 * j + 1] * pn[3 * i + 1]
                + gn[3 * j + 2] * pn[3 * i + 2];
        c = (1.0f - d) * invM;
    }
#pragma unroll
    for (int off = 32; off > 0; off >>= 1) c += __shfl_down(c, off, 64);
    __shared__ float partial[BLK / 64];
    if ((threadIdx.x & 63) == 0) partial[threadIdx.x >> 6] = c;
    __syncthreads();
    if (threadIdx.x == 0) {
        float s = 0.0f;
#pragma unroll
        for (int w = 0; w < BLK / 64; ++w) s += partial[w];
        atomicAdd(out, s);
    }
}

extern "C" void kernel_launch(void* const* d_in, const int* in_sizes, int n_in,
                              void* d_out, int out_size, void* d_ws, size_t ws_size,
                              hipStream_t stream) {
    const float* p  = (const float*)d_in[0];   // [N,3] predicted points
    const float* pn = (const float*)d_in[1];   // [N,3] predicted normals (unit)
    const float* g  = (const float*)d_in[2];   // [M,3] gt points
    const float* gn = (const float*)d_in[3];   // [M,3] gt normals (unit)
    const int N = in_sizes[0] / 3;             // 8192
    const int M = in_sizes[2] / 3;             // 32768

    ull* rowmin = (ull*)d_ws;                  // [N]
    ull* colmin = rowmin + N;                  // [M]
    float* out = (float*)d_out;

    hipMemsetAsync(d_ws, 0xFF, (size_t)(N + M) * sizeof(ull), stream);
    hipMemsetAsync(d_out, 0, sizeof(float), stream);

    const int rowSlices = M / SLICE;           // 64
    const int colSlices = N / SLICE;           // 16
    const int rowBlocks = (N / OWNERS) * rowSlices;  // 4*64 = 256
    const int colBlocks = (M / OWNERS) * colSlices;  // 16*16 = 256
    nn_argmin_dual<<<rowBlocks + colBlocks, BLK, 0, stream>>>(
        p, g, rowmin, colmin, rowBlocks, rowSlices, colSlices);

    int tot = N + M;
    finalize_kernel<<<(tot + BLK - 1) / BLK, BLK, 0, stream>>>(
        rowmin, colmin, pn, gn, out, N, M, 1.0f / N, 1.0f / M);
}

// Round 3
// 124.673 us; speedup vs baseline: 1.6139x; 1.0843x over previous
//
#include <hip/hip_runtime.h>
#include <stdint.h>

#define BLK 256
#define IPT 8                 // owner points per thread (8 independent min-chains)
#define OWNERS (BLK * IPT)    // 2048 owners per block
#define SLICE 256             // scanned-dimension slice per block (4 KB LDS)

typedef unsigned long long ull;

// Monotone float -> uint transform (preserves <, total order).
__device__ __forceinline__ unsigned int ford(float f) {
    int b = __float_as_int(f);
    return (b >= 0) ? ((unsigned)b ^ 0x80000000u) : ~(unsigned)b;
}

// Both NN directions in ONE launch. Blocks [0, rowBlocks) do owners=pred/scan=gt;
// the rest do owners=gt/scan=pred. For each owner o from A, argmin over scanned
// s of (|B_s|^2 - 2 A_o . B_s)  (drop the owner-constant |A_o|^2). Result merged
// via u64 atomicMin of (ordered_value<<32 | index) => numpy smallest-index ties.
// Grid sized to 2048 blocks = 8 blocks/CU = 32 waves/CU (full occupancy).
__global__ __launch_bounds__(BLK) void nn_argmin_dual(
    const float* __restrict__ p, const float* __restrict__ g,
    ull* __restrict__ rowmin, ull* __restrict__ colmin,
    int rowBlocks, int rowSlices, int colSlices)
{
    __shared__ float4 sb[SLICE];

    const float* A; const float* B; ull* outmin; int id, nSlices;
    if ((int)blockIdx.x < rowBlocks) {
        id = blockIdx.x;             A = p; B = g; outmin = rowmin; nSlices = rowSlices;
    } else {
        id = blockIdx.x - rowBlocks; A = g; B = p; outmin = colmin; nSlices = colSlices;
    }
    const int chunk = id / nSlices;
    const int slice = id - chunk * nSlices;
    const int s0 = slice * SLICE;

    // Stage the scanned slice (coords + |B|^2) into LDS. One barrier/block.
    if (threadIdx.x < SLICE) {
        int s = s0 + threadIdx.x;
        float bx = B[3 * s], by = B[3 * s + 1], bz = B[3 * s + 2];
        sb[threadIdx.x] = make_float4(bx, by, bz, bx * bx + by * by + bz * bz);
    }

    const int o0 = chunk * OWNERS + threadIdx.x;
    float ax[IPT], ay[IPT], az[IPT], best[IPT];
    int bidx[IPT];
#pragma unroll
    for (int r = 0; r < IPT; ++r) {
        int o = o0 + r * BLK;
        ax[r] = -2.0f * A[3 * o];
        ay[r] = -2.0f * A[3 * o + 1];
        az[r] = -2.0f * A[3 * o + 2];
        best[r] = __int_as_float(0x7f7fffff);
        bidx[r] = 0;
    }
    __syncthreads();

#pragma unroll 4
    for (int k = 0; k < SLICE; ++k) {
        float4 q = sb[k];        // wave-uniform broadcast read, no bank conflict
        int sj = s0 + k;         // scanned index increases monotonically
#pragma unroll
        for (int r = 0; r < IPT; ++r) {
            float v = fmaf(ax[r], q.x, fmaf(ay[r], q.y, fmaf(az[r], q.z, q.w)));
            if (v < best[r]) { best[r] = v; bidx[r] = sj; }  // strict <: first wins
        }
    }

#pragma unroll
    for (int r = 0; r < IPT; ++r) {
        ull packed = ((ull)ford(best[r]) << 32) | (unsigned)bidx[r];
        atomicMin(&outmin[o0 + r * BLK], packed);
    }
}

// Gather normals at argmin indices, accumulate mean(1 - dot) for both directions.
__global__ __launch_bounds__(BLK) void finalize_kernel(
    const ull* __restrict__ rowmin, const ull* __restrict__ colmin,
    const float* __restrict__ pn, const float* __restrict__ gn,
    float* __restrict__ out, int N, int M, float invN, float invM)
{
    int t = blockIdx.x * BLK + threadIdx.x;
    float c = 0.0f;
    if (t < N) {
        int j = (int)(rowmin[t] & 0xffffffffull);
        float d = pn[3 * t] * gn[3 * j] + pn[3 * t + 1] * gn[3 * j + 1]
                + pn[3 * t + 2] * gn[3 * j + 2];
        c = (1.0f - d) * invN;
    } else if (t < N + M) {
        int j = t - N;
        int i = (int)(colmin[j] & 0xffffffffull);
        float d = gn[3 * j] * pn[3 * i] + gn[3 * j + 1] * pn[3 * i + 1]
                + gn[3 * j + 2] * pn[3 * i + 2];
        c = (1.0f - d) * invM;
    }
#pragma unroll
    for (int off = 32; off > 0; off >>= 1) c += __shfl_down(c, off, 64);
    __shared__ float partial[BLK / 64];
    if ((threadIdx.x & 63) == 0) partial[threadIdx.x >> 6] = c;
    __syncthreads();
    if (threadIdx.x == 0) {
        float s = 0.0f;
#pragma unroll
        for (int w = 0; w < BLK / 64; ++w) s += partial[w];
        atomicAdd(out, s);
    }
}

extern "C" void kernel_launch(void* const* d_in, const int* in_sizes, int n_in,
                              void* d_out, int out_size, void* d_ws, size_t ws_size,
                              hipStream_t stream) {
    const float* p  = (const float*)d_in[0];   // [N,3] predicted points
    const float* pn = (const float*)d_in[1];   // [N,3] predicted normals (unit)
    const float* g  = (const float*)d_in[2];   // [M,3] gt points
    const float* gn = (const float*)d_in[3];   // [M,3] gt normals (unit)
    const int N = in_sizes[0] / 3;             // 8192
    const int M = in_sizes[2] / 3;             // 32768

    ull* rowmin = (ull*)d_ws;                  // [N]
    ull* colmin = rowmin + N;                  // [M]
    float* out = (float*)d_out;

    hipMemsetAsync(d_ws, 0xFF, (size_t)(N + M) * sizeof(ull), stream);
    hipMemsetAsync(d_out, 0, sizeof(float), stream);

    const int rowSlices = M / SLICE;                 // 128
    const int colSlices = N / SLICE;                 // 32
    const int rowBlocks = (N / OWNERS) * rowSlices;  // 4*128 = 512
    const int colBlocks = (M / OWNERS) * colSlices;  // 16*32 = 512
    nn_argmin_dual<<<rowBlocks + colBlocks, BLK, 0, stream>>>(
        p, g, rowmin, colmin, rowBlocks, rowSlices, colSlices);

    int tot = N + M;
    finalize_kernel<<<(tot + BLK - 1) / BLK, BLK, 0, stream>>>(
        rowmin, colmin, pn, gn, out, N, M, 1.0f / N, 1.0f / M);
}

// Round 4
// 114.939 us; speedup vs baseline: 1.7506x; 1.0847x over previous
//
#include <hip/hip_runtime.h>
#include <stdint.h>
#include <float.h>

#define BLK 256
#define IPT 8                 // owner points per thread (8 independent min-chains)
#define OWNERS (BLK * IPT)    // 2048 owners per block
#define SLICE 128             // scanned points per block (2 KB LDS)
#define SUB 64                // subtile granularity for deferred-index recovery

typedef unsigned long long ull;

// Monotone float -> uint transform (preserves <, total order) and inverse.
__device__ __forceinline__ unsigned int ford(float f) {
    int b = __float_as_int(f);
    return (b >= 0) ? ((unsigned)b ^ 0x80000000u) : ~(unsigned)b;
}
__device__ __forceinline__ float ford_inv(unsigned int u) {
    int b = (u & 0x80000000u) ? (int)(u ^ 0x80000000u) : (int)~u;
    return __int_as_float(b);
}

// Phase 1: min VALUE only (3 fma + v_min per pair, no index tracking in the hot
// loop). Per 64-point subtile, record the subtile base if the running min
// improved (strict < : first-improving subtile wins, matching numpy ties).
// Merge via u64 atomicMin of (ford(best)<<32 | subtile_base): equal values
// resolve to the smallest base = first occurrence. Exact index recovered in
// finalize by re-scanning the 64-point subtile with a bitwise-identical chain.
__global__ __launch_bounds__(BLK) void nn_min_dual(
    const float* __restrict__ p, const float* __restrict__ g,
    ull* __restrict__ rowmin, ull* __restrict__ colmin,
    int rowBlocks, int rowSlices, int colSlices)
{
    __shared__ float4 sb[SLICE];

    const float* A; const float* B; ull* outmin; int id, nSlices;
    if ((int)blockIdx.x < rowBlocks) {
        id = blockIdx.x;             A = p; B = g; outmin = rowmin; nSlices = rowSlices;
    } else {
        id = blockIdx.x - rowBlocks; A = g; B = p; outmin = colmin; nSlices = colSlices;
    }
    const int chunk = id / nSlices;
    const int slice = id - chunk * nSlices;
    const int s0 = slice * SLICE;

    // Stage slice (coords + |B|^2). Explicit fmaf: finalize recomputes the
    // identical expression so bit-exact equality holds.
    if (threadIdx.x < SLICE) {
        int s = s0 + threadIdx.x;
        float bx = B[3 * s], by = B[3 * s + 1], bz = B[3 * s + 2];
        float w = fmaf(bz, bz, fmaf(by, by, bx * bx));
        sb[threadIdx.x] = make_float4(bx, by, bz, w);
    }

    const int o0 = chunk * OWNERS + threadIdx.x;
    float ax[IPT], ay[IPT], az[IPT], best[IPT];
    int base[IPT];
#pragma unroll
    for (int r = 0; r < IPT; ++r) {
        int o = o0 + r * BLK;
        ax[r] = -2.0f * A[3 * o];
        ay[r] = -2.0f * A[3 * o + 1];
        az[r] = -2.0f * A[3 * o + 2];
        best[r] = FLT_MAX;
        base[r] = s0;
    }
    __syncthreads();

    for (int st = 0; st < SLICE; st += SUB) {
        float prev[IPT];
#pragma unroll
        for (int r = 0; r < IPT; ++r) prev[r] = best[r];
#pragma unroll 4
        for (int k = st; k < st + SUB; ++k) {
            float4 q = sb[k];    // wave-uniform broadcast read
#pragma unroll
            for (int r = 0; r < IPT; ++r) {
                float v = fmaf(ax[r], q.x, fmaf(ay[r], q.y, fmaf(az[r], q.z, q.w)));
                best[r] = fminf(best[r], v);
            }
        }
#pragma unroll
        for (int r = 0; r < IPT; ++r)
            if (best[r] < prev[r]) base[r] = s0 + st;   // strict <: first subtile wins
    }

#pragma unroll
    for (int r = 0; r < IPT; ++r) {
        ull packed = ((ull)ford(best[r]) << 32) | (unsigned)base[r];
        atomicMin(&outmin[o0 + r * BLK], packed);
    }
}

// Phase 2 + finalize: per owner, re-scan winning 64-pt subtile with the exact
// same fma chain to recover the first index attaining the min; gather normal,
// accumulate mean(1 - dot) for both directions.
__global__ __launch_bounds__(BLK) void finalize_kernel(
    const ull* __restrict__ rowmin, const ull* __restrict__ colmin,
    const float* __restrict__ p, const float* __restrict__ g,
    const float* __restrict__ pn, const float* __restrict__ gn,
    float* __restrict__ out, int N, int M, float invN, float invM)
{
    int t = blockIdx.x * BLK + threadIdx.x;
    float c = 0.0f;
    if (t < N + M) {
        const float* A; const float* B; const float* An; const float* Bn;
        ull packed; int o; float inv;
        if (t < N) { o = t;     A = p; B = g; An = pn; Bn = gn; packed = rowmin[o]; inv = invN; }
        else       { o = t - N; A = g; B = p; An = gn; Bn = pn; packed = colmin[o]; inv = invM; }

        float ax = -2.0f * A[3 * o];
        float ay = -2.0f * A[3 * o + 1];
        float az = -2.0f * A[3 * o + 2];
        float bestf = ford_inv((unsigned int)(packed >> 32));
        int base = (int)(packed & 0xffffffffull);

        int idx = base;
        for (int j = 0; j < SUB; ++j) {
            int s = base + j;
            float bx = B[3 * s], by = B[3 * s + 1], bz = B[3 * s + 2];
            float w = fmaf(bz, bz, fmaf(by, by, bx * bx));
            float v = fmaf(ax, bx, fmaf(ay, by, fmaf(az, bz, w)));
            if (v == bestf) { idx = s; break; }   // bit-exact recompute; first match
        }

        float d = An[3 * o] * Bn[3 * idx] + An[3 * o + 1] * Bn[3 * idx + 1]
                + An[3 * o + 2] * Bn[3 * idx + 2];
        c = (1.0f - d) * inv;
    }
#pragma unroll
    for (int off = 32; off > 0; off >>= 1) c += __shfl_down(c, off, 64);
    __shared__ float partial[BLK / 64];
    if ((threadIdx.x & 63) == 0) partial[threadIdx.x >> 6] = c;
    __syncthreads();
    if (threadIdx.x == 0) {
        float s = 0.0f;
#pragma unroll
        for (int w = 0; w < BLK / 64; ++w) s += partial[w];
        atomicAdd(out, s);
    }
}

extern "C" void kernel_launch(void* const* d_in, const int* in_sizes, int n_in,
                              void* d_out, int out_size, void* d_ws, size_t ws_size,
                              hipStream_t stream) {
    const float* p  = (const float*)d_in[0];   // [N,3] predicted points
    const float* pn = (const float*)d_in[1];   // [N,3] predicted normals (unit)
    const float* g  = (const float*)d_in[2];   // [M,3] gt points
    const float* gn = (const float*)d_in[3];   // [M,3] gt normals (unit)
    const int N = in_sizes[0] / 3;             // 8192
    const int M = in_sizes[2] / 3;             // 32768

    ull* rowmin = (ull*)d_ws;                  // [N]
    ull* colmin = rowmin + N;                  // [M]
    float* out = (float*)d_out;

    hipMemsetAsync(d_ws, 0xFF, (size_t)(N + M) * sizeof(ull), stream);
    hipMemsetAsync(d_out, 0, sizeof(float), stream);

    const int rowSlices = M / SLICE;                 // 256
    const int colSlices = N / SLICE;                 // 64
    const int rowBlocks = (N / OWNERS) * rowSlices;  // 4*256  = 1024
    const int colBlocks = (M / OWNERS) * colSlices;  // 16*64  = 1024
    nn_min_dual<<<rowBlocks + colBlocks, BLK, 0, stream>>>(
        p, g, rowmin, colmin, rowBlocks, rowSlices, colSlices);

    int tot = N + M;
    finalize_kernel<<<(tot + BLK - 1) / BLK, BLK, 0, stream>>>(
        rowmin, colmin, p, g, pn, gn, out, N, M, 1.0f / N, 1.0f / M);
}